// Round 1
// baseline (223.680 us; speedup 1.0000x reference)
//
#include <hip/hip_runtime.h>
#include <stdint.h>

static constexpr uint32_t SEQN = 4194304u;
static constexpr uint32_t BINS = 65536u;

__global__ __launch_bounds__(256) void k_zero(uint32_t* __restrict__ hist) {
  uint32_t i = blockIdx.x * 256u + threadIdx.x;
  if (i < BINS) hist[i] = 0u;
}

__global__ __launch_bounds__(256) void k_hist(const float4* __restrict__ in4,
                                              uint32_t* __restrict__ hist) {
  uint32_t r = blockIdx.x * 256u + threadIdx.x;
  if (r >= SEQN) return;
  uint32_t key = 0u;
#pragma unroll
  for (uint32_t q = 0; q < 4u; ++q) {
    float4 v = in4[(size_t)r * 4u + q];
    uint32_t nib = ((uint32_t)v.x << 3) | ((uint32_t)v.y << 2) |
                   ((uint32_t)v.z << 1) | (uint32_t)v.w;
    key = (key << 4) | nib;  // MSB-first fold
  }
  atomicAdd(&hist[key], 1u);
}

// scan phase 1: 64 blocks x 256 threads; each thread sums 4 bins; block total out
__global__ __launch_bounds__(256) void k_scan1(const uint32_t* __restrict__ hist,
                                               uint32_t* __restrict__ blkTot) {
  uint32_t tid = threadIdx.x, blk = blockIdx.x;
  uint32_t b0 = blk * 1024u + tid * 4u;
  uint32_t s = hist[b0] + hist[b0 + 1] + hist[b0 + 2] + hist[b0 + 3];
  for (int d = 1; d < 64; d <<= 1) s += __shfl_xor(s, d, 64);
  __shared__ uint32_t wt[4];
  if ((tid & 63u) == 0u) wt[tid >> 6] = s;
  __syncthreads();
  if (tid == 0u) blkTot[blk] = wt[0] + wt[1] + wt[2] + wt[3];
}

// scan phase 2: 1 wave scans the 64 block totals (exclusive, in place)
__global__ __launch_bounds__(64) void k_scan2(uint32_t* __restrict__ blkTot) {
  uint32_t t = threadIdx.x;
  uint32_t v = blkTot[t];
  uint32_t incl = v;
  for (int d = 1; d < 64; d <<= 1) {
    uint32_t n = __shfl_up(incl, d, 64);
    if (t >= (uint32_t)d) incl += n;
  }
  blkTot[t] = incl - v;  // exclusive
}

// scan phase 3: write per-bin exclusive offsets
__global__ __launch_bounds__(256) void k_scan3(const uint32_t* __restrict__ hist,
                                               const uint32_t* __restrict__ blkBase,
                                               uint32_t* __restrict__ offs) {
  uint32_t tid = threadIdx.x, blk = blockIdx.x;
  uint32_t lane = tid & 63u, wid = tid >> 6;
  uint32_t b0 = blk * 1024u + tid * 4u;
  uint32_t c0 = hist[b0], c1 = hist[b0 + 1], c2 = hist[b0 + 2], c3 = hist[b0 + 3];
  uint32_t s = c0 + c1 + c2 + c3;
  uint32_t incl = s;
  for (int d = 1; d < 64; d <<= 1) {
    uint32_t n = __shfl_up(incl, d, 64);
    if (lane >= (uint32_t)d) incl += n;
  }
  __shared__ uint32_t wt[4];
  if (lane == 63u) wt[wid] = incl;
  __syncthreads();
  uint32_t wbase = 0u;
  for (uint32_t w = 0; w < wid; ++w) wbase += wt[w];
  uint32_t base = blkBase[blk] + wbase + (incl - s);  // exclusive thread base
  offs[b0] = base;
  offs[b0 + 1] = base + c0;
  offs[b0 + 2] = base + c0 + c1;
  offs[b0 + 3] = base + c0 + c1 + c2;
}

// writer: 2048 blocks x 256 threads, 32 keys per block.
// Row-relative quad index == tid&3 (stride 256 preserves j mod 4), so each
// lane's pattern float4 is loop-invariant — no runtime-indexed array.
__global__ __launch_bounds__(256) void k_write(const uint32_t* __restrict__ hist,
                                               const uint32_t* __restrict__ offs,
                                               float4* __restrict__ out4) {
  __shared__ uint32_t s_off[32], s_cnt[32];
  uint32_t tid = threadIdx.x, blk = blockIdx.x;
  if (tid < 32u) {
    uint32_t k = blk * 32u + tid;
    s_off[tid] = offs[k];
    s_cnt[tid] = hist[k];
  }
  __syncthreads();
  uint32_t q = tid & 3u;
  for (uint32_t kk = 0; kk < 32u; ++kk) {
    uint32_t k = blk * 32u + kk;
    uint32_t off = s_off[kk], cnt = s_cnt[kk];
    float4 pat;
    pat.x = (float)((k >> (15u - (q * 4u + 0u))) & 1u);
    pat.y = (float)((k >> (15u - (q * 4u + 1u))) & 1u);
    pat.z = (float)((k >> (15u - (q * 4u + 2u))) & 1u);
    pat.w = (float)((k >> (15u - (q * 4u + 3u))) & 1u);
    size_t base = (size_t)off * 4u;
    uint32_t tot = cnt * 4u;
    for (uint32_t j = tid; j < tot; j += 256u) out4[base + j] = pat;
  }
}

extern "C" void kernel_launch(void* const* d_in, const int* in_sizes, int n_in,
                              void* d_out, int out_size, void* d_ws, size_t ws_size,
                              hipStream_t stream) {
  const float4* in4 = (const float4*)d_in[0];
  float4* out4 = (float4*)d_out;
  uint32_t* hist = (uint32_t*)d_ws;    // 65536 u32
  uint32_t* offs = hist + BINS;        // 65536 u32
  uint32_t* blkTot = offs + BINS;      // 64 u32

  k_zero<<<BINS / 256, 256, 0, stream>>>(hist);
  k_hist<<<SEQN / 256, 256, 0, stream>>>(in4, hist);
  k_scan1<<<64, 256, 0, stream>>>(hist, blkTot);
  k_scan2<<<1, 64, 0, stream>>>(blkTot);
  k_scan3<<<64, 256, 0, stream>>>(hist, blkTot, offs);
  k_write<<<BINS / 32, 256, 0, stream>>>(hist, offs, out4);
}

// Round 2
// 155.892 us; speedup vs baseline: 1.4348x; 1.4348x over previous
//
#include <hip/hip_runtime.h>
#include <stdint.h>

static constexpr uint32_t SEQN = 4194304u;
static constexpr uint32_t BINS = 65536u;
static constexpr uint32_t HWORDS = BINS / 2u;   // packed u16 pairs
static constexpr uint32_t NBLK = 256u;          // 1 per CU (128 KiB LDS each)
static constexpr uint32_t NTHR = 1024u;
static constexpr uint32_t ROWS_PER_BLK = SEQN / NBLK;  // 16384 (< 65536: u16 safe)

// ---------- LDS-privatized histogram ----------
__global__ __launch_bounds__(NTHR) void k_hist_lds(const float4* __restrict__ in4,
                                                   uint32_t* __restrict__ partial) {
  __shared__ uint32_t h[HWORDS];  // 128 KiB: bins 2w (lo16) and 2w+1 (hi16)
  uint32_t tid = threadIdx.x, blk = blockIdx.x;
  for (uint32_t i = tid; i < HWORDS; i += NTHR) h[i] = 0u;
  __syncthreads();
  uint32_t row0 = blk * ROWS_PER_BLK;
#pragma unroll 2
  for (uint32_t r = row0 + tid; r < row0 + ROWS_PER_BLK; r += NTHR) {
    const float4* p = in4 + (size_t)r * 4u;
    float4 a = p[0], b = p[1], c = p[2], d = p[3];
    // MSB-first fold: val = val*2 + bit (exact, 16 FMAs + 1 cvt)
    float kf = a.x;
    kf = kf * 2.0f + a.y; kf = kf * 2.0f + a.z; kf = kf * 2.0f + a.w;
    kf = kf * 2.0f + b.x; kf = kf * 2.0f + b.y; kf = kf * 2.0f + b.z; kf = kf * 2.0f + b.w;
    kf = kf * 2.0f + c.x; kf = kf * 2.0f + c.y; kf = kf * 2.0f + c.z; kf = kf * 2.0f + c.w;
    kf = kf * 2.0f + d.x; kf = kf * 2.0f + d.y; kf = kf * 2.0f + d.z; kf = kf * 2.0f + d.w;
    uint32_t key = (uint32_t)kf;
    atomicAdd(&h[key >> 1], 1u << ((key & 1u) << 4));
  }
  __syncthreads();
  uint32_t* dst = partial + (size_t)blk * HWORDS;
  for (uint32_t i = tid; i < HWORDS; i += NTHR) dst[i] = h[i];
}

__global__ __launch_bounds__(256) void k_reduce(const uint32_t* __restrict__ partial,
                                                uint32_t* __restrict__ hist) {
  uint32_t w = blockIdx.x * 256u + threadIdx.x;  // 0..HWORDS-1
  uint32_t lo = 0u, hi = 0u;
#pragma unroll 4
  for (uint32_t b = 0; b < NBLK; ++b) {
    uint32_t v = partial[(size_t)b * HWORDS + w];
    lo += v & 0xFFFFu;
    hi += v >> 16;
  }
  ((uint2*)hist)[w] = make_uint2(lo, hi);
}

// ---------- fallback global-atomic histogram (small ws) ----------
__global__ __launch_bounds__(256) void k_zero(uint32_t* __restrict__ hist) {
  uint32_t i = blockIdx.x * 256u + threadIdx.x;
  if (i < BINS) hist[i] = 0u;
}

__global__ __launch_bounds__(256) void k_hist(const float4* __restrict__ in4,
                                              uint32_t* __restrict__ hist) {
  uint32_t r = blockIdx.x * 256u + threadIdx.x;
  if (r >= SEQN) return;
  uint32_t key = 0u;
#pragma unroll
  for (uint32_t q = 0; q < 4u; ++q) {
    float4 v = in4[(size_t)r * 4u + q];
    uint32_t nib = ((uint32_t)v.x << 3) | ((uint32_t)v.y << 2) |
                   ((uint32_t)v.z << 1) | (uint32_t)v.w;
    key = (key << 4) | nib;
  }
  atomicAdd(&hist[key], 1u);
}

// ---------- scan (exclusive, 65536 bins) ----------
__global__ __launch_bounds__(256) void k_scan1(const uint32_t* __restrict__ hist,
                                               uint32_t* __restrict__ blkTot) {
  uint32_t tid = threadIdx.x, blk = blockIdx.x;
  uint32_t b0 = blk * 1024u + tid * 4u;
  uint32_t s = hist[b0] + hist[b0 + 1] + hist[b0 + 2] + hist[b0 + 3];
  for (int d = 1; d < 64; d <<= 1) s += __shfl_xor(s, d, 64);
  __shared__ uint32_t wt[4];
  if ((tid & 63u) == 0u) wt[tid >> 6] = s;
  __syncthreads();
  if (tid == 0u) blkTot[blk] = wt[0] + wt[1] + wt[2] + wt[3];
}

__global__ __launch_bounds__(64) void k_scan2(uint32_t* __restrict__ blkTot) {
  uint32_t t = threadIdx.x;
  uint32_t v = blkTot[t];
  uint32_t incl = v;
  for (int d = 1; d < 64; d <<= 1) {
    uint32_t n = __shfl_up(incl, d, 64);
    if (t >= (uint32_t)d) incl += n;
  }
  blkTot[t] = incl - v;
}

__global__ __launch_bounds__(256) void k_scan3(const uint32_t* __restrict__ hist,
                                               const uint32_t* __restrict__ blkBase,
                                               uint32_t* __restrict__ offs) {
  uint32_t tid = threadIdx.x, blk = blockIdx.x;
  uint32_t lane = tid & 63u, wid = tid >> 6;
  uint32_t b0 = blk * 1024u + tid * 4u;
  uint32_t c0 = hist[b0], c1 = hist[b0 + 1], c2 = hist[b0 + 2], c3 = hist[b0 + 3];
  uint32_t s = c0 + c1 + c2 + c3;
  uint32_t incl = s;
  for (int d = 1; d < 64; d <<= 1) {
    uint32_t n = __shfl_up(incl, d, 64);
    if (lane >= (uint32_t)d) incl += n;
  }
  __shared__ uint32_t wt[4];
  if (lane == 63u) wt[wid] = incl;
  __syncthreads();
  uint32_t wbase = 0u;
  for (uint32_t w = 0; w < wid; ++w) wbase += wt[w];
  uint32_t base = blkBase[blk] + wbase + (incl - s);
  offs[b0] = base;
  offs[b0 + 1] = base + c0;
  offs[b0 + 2] = base + c0 + c1;
  offs[b0 + 3] = base + c0 + c1 + c2;
}

// ---------- writer: stream each key's pattern count[k] times ----------
__global__ __launch_bounds__(256) void k_write(const uint32_t* __restrict__ hist,
                                               const uint32_t* __restrict__ offs,
                                               float4* __restrict__ out4) {
  __shared__ uint32_t s_off[32], s_cnt[32];
  uint32_t tid = threadIdx.x, blk = blockIdx.x;
  if (tid < 32u) {
    uint32_t k = blk * 32u + tid;
    s_off[tid] = offs[k];
    s_cnt[tid] = hist[k];
  }
  __syncthreads();
  uint32_t q = tid & 3u;
  for (uint32_t kk = 0; kk < 32u; ++kk) {
    uint32_t k = blk * 32u + kk;
    uint32_t off = s_off[kk], cnt = s_cnt[kk];
    float4 pat;
    pat.x = (float)((k >> (15u - (q * 4u + 0u))) & 1u);
    pat.y = (float)((k >> (15u - (q * 4u + 1u))) & 1u);
    pat.z = (float)((k >> (15u - (q * 4u + 2u))) & 1u);
    pat.w = (float)((k >> (15u - (q * 4u + 3u))) & 1u);
    size_t base = (size_t)off * 4u;
    uint32_t tot = cnt * 4u;
    for (uint32_t j = tid; j < tot; j += 256u) out4[base + j] = pat;
  }
}

extern "C" void kernel_launch(void* const* d_in, const int* in_sizes, int n_in,
                              void* d_out, int out_size, void* d_ws, size_t ws_size,
                              hipStream_t stream) {
  const float4* in4 = (const float4*)d_in[0];
  float4* out4 = (float4*)d_out;
  uint32_t* hist = (uint32_t*)d_ws;          // 65536 u32
  uint32_t* offs = hist + BINS;              // 65536 u32
  uint32_t* blkTot = offs + BINS;            // 64 u32 (pad to 1024)
  uint32_t* partial = blkTot + 1024u;        // NBLK * HWORDS u32 = 32 MiB

  size_t need = ((size_t)2 * BINS + 1024u + (size_t)NBLK * HWORDS) * 4u;
  if (ws_size >= need) {
    k_hist_lds<<<NBLK, NTHR, 0, stream>>>(in4, partial);
    k_reduce<<<HWORDS / 256, 256, 0, stream>>>(partial, hist);
  } else {
    k_zero<<<BINS / 256, 256, 0, stream>>>(hist);
    k_hist<<<SEQN / 256, 256, 0, stream>>>(in4, hist);
  }
  k_scan1<<<64, 256, 0, stream>>>(hist, blkTot);
  k_scan2<<<1, 64, 0, stream>>>(blkTot);
  k_scan3<<<64, 256, 0, stream>>>(hist, blkTot, offs);
  k_write<<<BINS / 32, 256, 0, stream>>>(hist, offs, out4);
}

// Round 3
// 149.613 us; speedup vs baseline: 1.4951x; 1.0420x over previous
//
#include <hip/hip_runtime.h>
#include <stdint.h>

static constexpr uint32_t SEQN = 4194304u;
static constexpr uint32_t BINS = 65536u;
static constexpr uint32_t QWORDS = BINS / 4u;       // u8x4-packed words per block
static constexpr uint32_t NBLK = 512u;              // 2 per CU (64 KiB LDS each)
static constexpr uint32_t NTHR = 1024u;
static constexpr uint32_t ROWS_PER_BLK = SEQN / NBLK;  // 8192 (per-(blk,bin) << 255)
static constexpr uint32_t NSEG = 8u;                // reduce tree fan-in 64

// ---------- LDS-privatized histogram, u8x4 packed ----------
__global__ __launch_bounds__(NTHR) void k_hist_lds(const float4* __restrict__ in4,
                                                   uint32_t* __restrict__ partial) {
  __shared__ uint32_t h[QWORDS];  // 64 KiB: bins 4w+0..4w+3 as u8 lanes
  uint32_t tid = threadIdx.x, blk = blockIdx.x;
  uint4* hv = (uint4*)h;
  for (uint32_t i = tid; i < QWORDS / 4u; i += NTHR) hv[i] = make_uint4(0u, 0u, 0u, 0u);
  __syncthreads();
  uint32_t row0 = blk * ROWS_PER_BLK;
#pragma unroll 2
  for (uint32_t r = row0 + tid; r < row0 + ROWS_PER_BLK; r += NTHR) {
    const float4* p = in4 + (size_t)r * 4u;
    float4 a = p[0], b = p[1], c = p[2], d = p[3];
    float kf = a.x;
    kf = kf * 2.0f + a.y; kf = kf * 2.0f + a.z; kf = kf * 2.0f + a.w;
    kf = kf * 2.0f + b.x; kf = kf * 2.0f + b.y; kf = kf * 2.0f + b.z; kf = kf * 2.0f + b.w;
    kf = kf * 2.0f + c.x; kf = kf * 2.0f + c.y; kf = kf * 2.0f + c.z; kf = kf * 2.0f + c.w;
    kf = kf * 2.0f + d.x; kf = kf * 2.0f + d.y; kf = kf * 2.0f + d.z; kf = kf * 2.0f + d.w;
    uint32_t key = (uint32_t)kf;
    atomicAdd(&h[key >> 2], 1u << ((key & 3u) << 3));
  }
  __syncthreads();
  uint4* dst = (uint4*)(partial + (size_t)blk * QWORDS);
  for (uint32_t i = tid; i < QWORDS / 4u; i += NTHR) dst[i] = hv[i];
}

// ---------- reduce stage A: 8 segments x 64 partials each ----------
__global__ __launch_bounds__(256) void k_reduceA(const uint32_t* __restrict__ partial,
                                                 uint2* __restrict__ seg) {
  uint32_t tid = threadIdx.x, blk = blockIdx.x;
  uint32_t s = blk >> 6, wg = blk & 63u;
  uint32_t w = wg * 256u + tid;
  uint32_t acc_e = 0u, acc_o = 0u;  // packed u16 pairs: (bin4w+0,bin4w+2) / (4w+1,4w+3)
  uint32_t p0 = s * (NBLK / NSEG);
#pragma unroll 8
  for (uint32_t p = p0; p < p0 + NBLK / NSEG; ++p) {
    uint32_t v = partial[(size_t)p * QWORDS + w];
    acc_e += v & 0x00FF00FFu;
    acc_o += (v >> 8) & 0x00FF00FFu;
  }
  seg[(size_t)s * QWORDS + w] = make_uint2(acc_e, acc_o);
}

// ---------- reduce stage B fused with scan1: hist + per-1024-bin block totals ----------
__global__ __launch_bounds__(256) void k_scanA(const uint2* __restrict__ seg,
                                               uint32_t* __restrict__ hist,
                                               uint32_t* __restrict__ blkTot) {
  uint32_t tid = threadIdx.x, blk = blockIdx.x;
  uint32_t w = blk * 256u + tid;  // word index; bins 4w..4w+3
  uint32_t e = 0u, o = 0u;
#pragma unroll
  for (uint32_t s = 0; s < NSEG; ++s) {
    uint2 v = seg[(size_t)s * QWORDS + w];
    e += v.x;
    o += v.y;
  }
  uint32_t c0 = e & 0xFFFFu, c2 = e >> 16, c1 = o & 0xFFFFu, c3 = o >> 16;
  ((uint4*)hist)[w] = make_uint4(c0, c1, c2, c3);
  uint32_t ssum = c0 + c1 + c2 + c3;
  for (int d = 1; d < 64; d <<= 1) ssum += __shfl_xor(ssum, d, 64);
  __shared__ uint32_t wt[4];
  if ((tid & 63u) == 0u) wt[tid >> 6] = ssum;
  __syncthreads();
  if (tid == 0u) blkTot[blk] = wt[0] + wt[1] + wt[2] + wt[3];
}

// ---------- fallback global-atomic histogram (small ws) ----------
__global__ __launch_bounds__(256) void k_zero(uint32_t* __restrict__ hist) {
  uint32_t i = blockIdx.x * 256u + threadIdx.x;
  if (i < BINS) hist[i] = 0u;
}

__global__ __launch_bounds__(256) void k_hist(const float4* __restrict__ in4,
                                              uint32_t* __restrict__ hist) {
  uint32_t r = blockIdx.x * 256u + threadIdx.x;
  if (r >= SEQN) return;
  uint32_t key = 0u;
#pragma unroll
  for (uint32_t q = 0; q < 4u; ++q) {
    float4 v = in4[(size_t)r * 4u + q];
    uint32_t nib = ((uint32_t)v.x << 3) | ((uint32_t)v.y << 2) |
                   ((uint32_t)v.z << 1) | (uint32_t)v.w;
    key = (key << 4) | nib;
  }
  atomicAdd(&hist[key], 1u);
}

__global__ __launch_bounds__(256) void k_scan1(const uint32_t* __restrict__ hist,
                                               uint32_t* __restrict__ blkTot) {
  uint32_t tid = threadIdx.x, blk = blockIdx.x;
  uint32_t b0 = blk * 1024u + tid * 4u;
  uint32_t s = hist[b0] + hist[b0 + 1] + hist[b0 + 2] + hist[b0 + 3];
  for (int d = 1; d < 64; d <<= 1) s += __shfl_xor(s, d, 64);
  __shared__ uint32_t wt[4];
  if ((tid & 63u) == 0u) wt[tid >> 6] = s;
  __syncthreads();
  if (tid == 0u) blkTot[blk] = wt[0] + wt[1] + wt[2] + wt[3];
}

// ---------- scan tail ----------
__global__ __launch_bounds__(64) void k_scan2(uint32_t* __restrict__ blkTot) {
  uint32_t t = threadIdx.x;
  uint32_t v = blkTot[t];
  uint32_t incl = v;
  for (int d = 1; d < 64; d <<= 1) {
    uint32_t n = __shfl_up(incl, d, 64);
    if (t >= (uint32_t)d) incl += n;
  }
  blkTot[t] = incl - v;
}

__global__ __launch_bounds__(256) void k_scan3(const uint32_t* __restrict__ hist,
                                               const uint32_t* __restrict__ blkBase,
                                               uint32_t* __restrict__ offs) {
  uint32_t tid = threadIdx.x, blk = blockIdx.x;
  uint32_t lane = tid & 63u, wid = tid >> 6;
  uint32_t b0 = blk * 1024u + tid * 4u;
  uint4 c = ((const uint4*)hist)[b0 >> 2];
  uint32_t s = c.x + c.y + c.z + c.w;
  uint32_t incl = s;
  for (int d = 1; d < 64; d <<= 1) {
    uint32_t n = __shfl_up(incl, d, 64);
    if (lane >= (uint32_t)d) incl += n;
  }
  __shared__ uint32_t wt[4];
  if (lane == 63u) wt[wid] = incl;
  __syncthreads();
  uint32_t wbase = 0u;
  for (uint32_t w = 0; w < wid; ++w) wbase += wt[w];
  uint32_t base = blkBase[blk] + wbase + (incl - s);
  ((uint4*)offs)[b0 >> 2] = make_uint4(base, base + c.x, base + c.x + c.y,
                                       base + c.x + c.y + c.z);
}

// ---------- writer: stream each key's pattern count[k] times ----------
__global__ __launch_bounds__(256) void k_write(const uint32_t* __restrict__ hist,
                                               const uint32_t* __restrict__ offs,
                                               float4* __restrict__ out4) {
  __shared__ uint32_t s_off[32], s_cnt[32];
  uint32_t tid = threadIdx.x, blk = blockIdx.x;
  if (tid < 32u) {
    uint32_t k = blk * 32u + tid;
    s_off[tid] = offs[k];
    s_cnt[tid] = hist[k];
  }
  __syncthreads();
  uint32_t q = tid & 3u;
  for (uint32_t kk = 0; kk < 32u; ++kk) {
    uint32_t k = blk * 32u + kk;
    uint32_t off = s_off[kk], cnt = s_cnt[kk];
    float4 pat;
    pat.x = (float)((k >> (15u - (q * 4u + 0u))) & 1u);
    pat.y = (float)((k >> (15u - (q * 4u + 1u))) & 1u);
    pat.z = (float)((k >> (15u - (q * 4u + 2u))) & 1u);
    pat.w = (float)((k >> (15u - (q * 4u + 3u))) & 1u);
    size_t base = (size_t)off * 4u;
    uint32_t tot = cnt * 4u;
    for (uint32_t j = tid; j < tot; j += 256u) out4[base + j] = pat;
  }
}

extern "C" void kernel_launch(void* const* d_in, const int* in_sizes, int n_in,
                              void* d_out, int out_size, void* d_ws, size_t ws_size,
                              hipStream_t stream) {
  const float4* in4 = (const float4*)d_in[0];
  float4* out4 = (float4*)d_out;
  uint32_t* hist = (uint32_t*)d_ws;               // 65536 u32
  uint32_t* offs = hist + BINS;                   // 65536 u32
  uint32_t* blkTot = offs + BINS;                 // 64 u32 (pad to 1024)
  uint32_t* partial = blkTot + 1024u;             // NBLK * QWORDS u32 = 32 MiB
  uint2* seg = (uint2*)(partial + (size_t)NBLK * QWORDS);  // 8 * QWORDS uint2 = 1 MiB

  size_t need = ((size_t)2 * BINS + 1024u + (size_t)NBLK * QWORDS +
                 (size_t)NSEG * QWORDS * 2u) * 4u;
  if (ws_size >= need) {
    k_hist_lds<<<NBLK, NTHR, 0, stream>>>(in4, partial);
    k_reduceA<<<NSEG * 64, 256, 0, stream>>>(partial, seg);
    k_scanA<<<64, 256, 0, stream>>>(seg, hist, blkTot);
  } else {
    k_zero<<<BINS / 256, 256, 0, stream>>>(hist);
    k_hist<<<SEQN / 256, 256, 0, stream>>>(in4, hist);
    k_scan1<<<64, 256, 0, stream>>>(hist, blkTot);
  }
  k_scan2<<<1, 64, 0, stream>>>(blkTot);
  k_scan3<<<64, 256, 0, stream>>>(hist, blkTot, offs);
  k_write<<<BINS / 32, 256, 0, stream>>>(hist, offs, out4);
}

// Round 4
// 146.935 us; speedup vs baseline: 1.5223x; 1.0182x over previous
//
#include <hip/hip_runtime.h>
#include <stdint.h>

static constexpr uint32_t SEQN = 4194304u;
static constexpr uint32_t BINS = 65536u;
static constexpr uint32_t QWORDS = BINS / 4u;       // u8x4-packed words
static constexpr uint32_t NBLK = 512u;              // 2 per CU (64 KiB LDS each)
static constexpr uint32_t NTHR = 1024u;
static constexpr uint32_t ROWS_PER_BLK = SEQN / NBLK;  // 8192
static constexpr uint32_t NSEG = 8u;

// ---------- LDS-privatized histogram, fully-coalesced loads ----------
// lane handles one 16B quad; 4-lane shfl butterfly assembles the 16-bit key.
__global__ __launch_bounds__(NTHR) void k_hist_lds(const float4* __restrict__ in4,
                                                   uint32_t* __restrict__ partial) {
  __shared__ uint32_t h[QWORDS];  // 64 KiB u8x4 counters
  uint32_t tid = threadIdx.x, blk = blockIdx.x;
  uint4* hv = (uint4*)h;
  for (uint32_t i = tid; i < QWORDS / 4u; i += NTHR) hv[i] = make_uint4(0u, 0u, 0u, 0u);
  __syncthreads();
  uint32_t q = tid & 3u;
  uint32_t shift = 12u - (q << 2);        // quad q covers bits [4q,4q+4) MSB-first
  bool leader = (q == 0u);
  const float4* base = in4 + (size_t)blk * (ROWS_PER_BLK * 4u);
#pragma unroll 4
  for (uint32_t t = 0; t < (ROWS_PER_BLK * 4u) / NTHR; ++t) {  // 32 iters
    float4 v = base[(size_t)t * NTHR + tid];                   // contiguous 16 B/lane
    float nf = ((v.x * 2.0f + v.y) * 2.0f + v.z) * 2.0f + v.w; // nibble, exact
    uint32_t part = ((uint32_t)nf) << shift;
    part += __shfl_xor(part, 1, 64);
    part += __shfl_xor(part, 2, 64);      // all 4 lanes now hold the full key
    if (leader) atomicAdd(&h[part >> 2], 1u << ((part & 3u) << 3));
  }
  __syncthreads();
  uint4* dst = (uint4*)(partial + (size_t)blk * QWORDS);
  for (uint32_t i = tid; i < QWORDS / 4u; i += NTHR) dst[i] = hv[i];
}

// ---------- reduce stage A: 8 segments x 64 partials each ----------
__global__ __launch_bounds__(256) void k_reduceA(const uint32_t* __restrict__ partial,
                                                 uint2* __restrict__ seg) {
  uint32_t tid = threadIdx.x, blk = blockIdx.x;
  uint32_t s = blk >> 6, wg = blk & 63u;
  uint32_t w = wg * 256u + tid;
  uint32_t acc_e = 0u, acc_o = 0u;
  uint32_t p0 = s * (NBLK / NSEG);
#pragma unroll 8
  for (uint32_t p = p0; p < p0 + NBLK / NSEG; ++p) {
    uint32_t v = partial[(size_t)p * QWORDS + w];
    acc_e += v & 0x00FF00FFu;
    acc_o += (v >> 8) & 0x00FF00FFu;
  }
  seg[(size_t)s * QWORDS + w] = make_uint2(acc_e, acc_o);
}

// ---------- reduce stage B + per-1024-bin block totals ----------
__global__ __launch_bounds__(256) void k_scanA(const uint2* __restrict__ seg,
                                               uint32_t* __restrict__ hist,
                                               uint32_t* __restrict__ blkTot) {
  uint32_t tid = threadIdx.x, blk = blockIdx.x;
  uint32_t w = blk * 256u + tid;
  uint32_t e = 0u, o = 0u;
#pragma unroll
  for (uint32_t s = 0; s < NSEG; ++s) {
    uint2 v = seg[(size_t)s * QWORDS + w];
    e += v.x;
    o += v.y;
  }
  uint32_t c0 = e & 0xFFFFu, c2 = e >> 16, c1 = o & 0xFFFFu, c3 = o >> 16;
  ((uint4*)hist)[w] = make_uint4(c0, c1, c2, c3);
  uint32_t ssum = c0 + c1 + c2 + c3;
  for (int d = 1; d < 64; d <<= 1) ssum += __shfl_xor(ssum, d, 64);
  __shared__ uint32_t wt[4];
  if ((tid & 63u) == 0u) wt[tid >> 6] = ssum;
  __syncthreads();
  if (tid == 0u) blkTot[blk] = wt[0] + wt[1] + wt[2] + wt[3];
}

// ---------- fallback global-atomic histogram (small ws) ----------
__global__ __launch_bounds__(256) void k_zero(uint32_t* __restrict__ hist) {
  uint32_t i = blockIdx.x * 256u + threadIdx.x;
  if (i < BINS) hist[i] = 0u;
}

__global__ __launch_bounds__(256) void k_hist(const float4* __restrict__ in4,
                                              uint32_t* __restrict__ hist) {
  uint32_t r = blockIdx.x * 256u + threadIdx.x;
  if (r >= SEQN) return;
  uint32_t key = 0u;
#pragma unroll
  for (uint32_t qq = 0; qq < 4u; ++qq) {
    float4 v = in4[(size_t)r * 4u + qq];
    uint32_t nib = ((uint32_t)v.x << 3) | ((uint32_t)v.y << 2) |
                   ((uint32_t)v.z << 1) | (uint32_t)v.w;
    key = (key << 4) | nib;
  }
  atomicAdd(&hist[key], 1u);
}

__global__ __launch_bounds__(256) void k_scan1(const uint32_t* __restrict__ hist,
                                               uint32_t* __restrict__ blkTot) {
  uint32_t tid = threadIdx.x, blk = blockIdx.x;
  uint32_t b0 = blk * 1024u + tid * 4u;
  uint32_t s = hist[b0] + hist[b0 + 1] + hist[b0 + 2] + hist[b0 + 3];
  for (int d = 1; d < 64; d <<= 1) s += __shfl_xor(s, d, 64);
  __shared__ uint32_t wt[4];
  if ((tid & 63u) == 0u) wt[tid >> 6] = s;
  __syncthreads();
  if (tid == 0u) blkTot[blk] = wt[0] + wt[1] + wt[2] + wt[3];
}

// ---------- fused scan2+scan3: block base from blkTot, then per-bin offsets ----------
__global__ __launch_bounds__(256) void k_scanB(const uint32_t* __restrict__ hist,
                                               const uint32_t* __restrict__ blkTot,
                                               uint32_t* __restrict__ offs) {
  __shared__ uint32_t s_base;
  __shared__ uint32_t wt[4];
  uint32_t tid = threadIdx.x, blk = blockIdx.x;
  if (tid < 64u) {  // wave 0: exclusive prefix over the 64 block totals
    uint32_t v = blkTot[tid];
    uint32_t incl = v;
    for (int d = 1; d < 64; d <<= 1) {
      uint32_t n = __shfl_up(incl, d, 64);
      if (tid >= (uint32_t)d) incl += n;
    }
    if (tid == blk) s_base = incl - v;
  }
  __syncthreads();
  uint32_t lane = tid & 63u, wid = tid >> 6;
  uint32_t b0 = blk * 1024u + tid * 4u;
  uint4 c = ((const uint4*)hist)[b0 >> 2];
  uint32_t s = c.x + c.y + c.z + c.w;
  uint32_t incl = s;
  for (int d = 1; d < 64; d <<= 1) {
    uint32_t n = __shfl_up(incl, d, 64);
    if (lane >= (uint32_t)d) incl += n;
  }
  if (lane == 63u) wt[wid] = incl;
  __syncthreads();
  uint32_t wbase = 0u;
  for (uint32_t w = 0; w < wid; ++w) wbase += wt[w];
  uint32_t base = s_base + wbase + (incl - s);
  ((uint4*)offs)[b0 >> 2] = make_uint4(base, base + c.x, base + c.x + c.y,
                                       base + c.x + c.y + c.z);
}

// ---------- writer ----------
__global__ __launch_bounds__(256) void k_write(const uint32_t* __restrict__ hist,
                                               const uint32_t* __restrict__ offs,
                                               float4* __restrict__ out4) {
  __shared__ uint32_t s_off[32], s_cnt[32];
  uint32_t tid = threadIdx.x, blk = blockIdx.x;
  if (tid < 32u) {
    uint32_t k = blk * 32u + tid;
    s_off[tid] = offs[k];
    s_cnt[tid] = hist[k];
  }
  __syncthreads();
  uint32_t q = tid & 3u;
  for (uint32_t kk = 0; kk < 32u; ++kk) {
    uint32_t k = blk * 32u + kk;
    uint32_t off = s_off[kk], cnt = s_cnt[kk];
    float4 pat;
    pat.x = (float)((k >> (15u - (q * 4u + 0u))) & 1u);
    pat.y = (float)((k >> (15u - (q * 4u + 1u))) & 1u);
    pat.z = (float)((k >> (15u - (q * 4u + 2u))) & 1u);
    pat.w = (float)((k >> (15u - (q * 4u + 3u))) & 1u);
    size_t base = (size_t)off * 4u;
    uint32_t tot = cnt * 4u;
    for (uint32_t j = tid; j < tot; j += 256u) out4[base + j] = pat;
  }
}

extern "C" void kernel_launch(void* const* d_in, const int* in_sizes, int n_in,
                              void* d_out, int out_size, void* d_ws, size_t ws_size,
                              hipStream_t stream) {
  const float4* in4 = (const float4*)d_in[0];
  float4* out4 = (float4*)d_out;
  uint32_t* hist = (uint32_t*)d_ws;               // 65536 u32
  uint32_t* offs = hist + BINS;                   // 65536 u32
  uint32_t* blkTot = offs + BINS;                 // 64 u32 (pad to 1024)
  uint32_t* partial = blkTot + 1024u;             // NBLK * QWORDS u32 = 32 MiB
  uint2* seg = (uint2*)(partial + (size_t)NBLK * QWORDS);  // 1 MiB

  size_t need = ((size_t)2 * BINS + 1024u + (size_t)NBLK * QWORDS +
                 (size_t)NSEG * QWORDS * 2u) * 4u;
  if (ws_size >= need) {
    k_hist_lds<<<NBLK, NTHR, 0, stream>>>(in4, partial);
    k_reduceA<<<NSEG * 64, 256, 0, stream>>>(partial, seg);
    k_scanA<<<64, 256, 0, stream>>>(seg, hist, blkTot);
  } else {
    k_zero<<<BINS / 256, 256, 0, stream>>>(hist);
    k_hist<<<SEQN / 256, 256, 0, stream>>>(in4, hist);
    k_scan1<<<64, 256, 0, stream>>>(hist, blkTot);
  }
  k_scanB<<<64, 256, 0, stream>>>(hist, blkTot, offs);
  k_write<<<BINS / 32, 256, 0, stream>>>(hist, offs, out4);
}

// Round 5
// 143.204 us; speedup vs baseline: 1.5620x; 1.0261x over previous
//
#include <hip/hip_runtime.h>
#include <stdint.h>

static constexpr uint32_t SEQN = 4194304u;
static constexpr uint32_t BINS = 65536u;
static constexpr uint32_t QWORDS = BINS / 4u;       // u8x4-packed words
static constexpr uint32_t NBLK = 512u;              // 2 per CU (64 KiB LDS each)
static constexpr uint32_t NTHR = 1024u;
static constexpr uint32_t ROWS_PER_BLK = SEQN / NBLK;  // 8192

// ---------- LDS-privatized histogram, coalesced quad loads ----------
__global__ __launch_bounds__(NTHR) void k_hist_lds(const float4* __restrict__ in4,
                                                   uint32_t* __restrict__ partial) {
  __shared__ uint32_t h[QWORDS];  // 64 KiB u8x4 counters
  uint32_t tid = threadIdx.x, blk = blockIdx.x;
  uint4* hv = (uint4*)h;
  for (uint32_t i = tid; i < QWORDS / 4u; i += NTHR) hv[i] = make_uint4(0u, 0u, 0u, 0u);
  __syncthreads();
  uint32_t q = tid & 3u;
  uint32_t shift = 12u - (q << 2);        // quad q covers bits [4q,4q+4) MSB-first
  bool leader = (q == 0u);
  const float4* base = in4 + (size_t)blk * (ROWS_PER_BLK * 4u);
#pragma unroll 8
  for (uint32_t t = 0; t < (ROWS_PER_BLK * 4u) / NTHR; ++t) {  // 32 iters
    float4 v = base[(size_t)t * NTHR + tid];                   // contiguous 16 B/lane
    float nf = ((v.x * 2.0f + v.y) * 2.0f + v.z) * 2.0f + v.w; // nibble, exact
    uint32_t part = ((uint32_t)nf) << shift;
    part += __shfl_xor(part, 1, 64);
    part += __shfl_xor(part, 2, 64);      // all 4 lanes hold the full key
    if (leader) atomicAdd(&h[part >> 2], 1u << ((part & 3u) << 3));
  }
  __syncthreads();
  uint4* dst = (uint4*)(partial + (size_t)blk * QWORDS);
  for (uint32_t i = tid; i < QWORDS / 4u; i += NTHR) dst[i] = hv[i];
}

// ---------- fused reduce (512-fan-in) + hist + per-1024-bin totals ----------
__global__ __launch_bounds__(NTHR) void k_reduceB(const uint32_t* __restrict__ partial,
                                                  uint32_t* __restrict__ hist,
                                                  uint32_t* __restrict__ blkTot) {
  __shared__ uint2 acc[4][256];
  __shared__ uint32_t wt[4];
  uint32_t tid = threadIdx.x, blk = blockIdx.x;
  uint32_t wl = tid & 255u, g = tid >> 8;   // word-local, partial-group
  uint32_t w = blk * 256u + wl;             // word index; bins 4w..4w+3
  uint32_t e = 0u, o = 0u;                  // packed u16 pairs (4w,4w+2)/(4w+1,4w+3)
  uint32_t p0 = g * (NBLK / 4u);
#pragma unroll 8
  for (uint32_t p = p0; p < p0 + NBLK / 4u; ++p) {
    uint32_t v = partial[(size_t)p * QWORDS + w];
    e += v & 0x00FF00FFu;
    o += (v >> 8) & 0x00FF00FFu;
  }
  acc[g][wl] = make_uint2(e, o);
  __syncthreads();
  if (g == 0u) {
    uint2 a1 = acc[1][wl], a2 = acc[2][wl], a3 = acc[3][wl];
    e += a1.x + a2.x + a3.x;
    o += a1.y + a2.y + a3.y;
    uint32_t c0 = e & 0xFFFFu, c2 = e >> 16, c1 = o & 0xFFFFu, c3 = o >> 16;
    ((uint4*)hist)[w] = make_uint4(c0, c1, c2, c3);
    uint32_t ssum = c0 + c1 + c2 + c3;
    for (int d = 1; d < 64; d <<= 1) ssum += __shfl_xor(ssum, d, 64);
    if ((tid & 63u) == 0u) wt[tid >> 6] = ssum;
  }
  __syncthreads();
  if (tid == 0u) blkTot[blk] = wt[0] + wt[1] + wt[2] + wt[3];
}

// ---------- fallback global-atomic histogram (small ws) ----------
__global__ __launch_bounds__(256) void k_zero(uint32_t* __restrict__ hist) {
  uint32_t i = blockIdx.x * 256u + threadIdx.x;
  if (i < BINS) hist[i] = 0u;
}

__global__ __launch_bounds__(256) void k_hist(const float4* __restrict__ in4,
                                              uint32_t* __restrict__ hist) {
  uint32_t r = blockIdx.x * 256u + threadIdx.x;
  if (r >= SEQN) return;
  uint32_t key = 0u;
#pragma unroll
  for (uint32_t qq = 0; qq < 4u; ++qq) {
    float4 v = in4[(size_t)r * 4u + qq];
    uint32_t nib = ((uint32_t)v.x << 3) | ((uint32_t)v.y << 2) |
                   ((uint32_t)v.z << 1) | (uint32_t)v.w;
    key = (key << 4) | nib;
  }
  atomicAdd(&hist[key], 1u);
}

__global__ __launch_bounds__(256) void k_scan1(const uint32_t* __restrict__ hist,
                                               uint32_t* __restrict__ blkTot) {
  uint32_t tid = threadIdx.x, blk = blockIdx.x;
  uint32_t b0 = blk * 1024u + tid * 4u;
  uint32_t s = hist[b0] + hist[b0 + 1] + hist[b0 + 2] + hist[b0 + 3];
  for (int d = 1; d < 64; d <<= 1) s += __shfl_xor(s, d, 64);
  __shared__ uint32_t wt[4];
  if ((tid & 63u) == 0u) wt[tid >> 6] = s;
  __syncthreads();
  if (tid == 0u) blkTot[blk] = wt[0] + wt[1] + wt[2] + wt[3];
}

// ---------- fused scan: block base from blkTot, then per-bin offsets ----------
__global__ __launch_bounds__(256) void k_scanB(const uint32_t* __restrict__ hist,
                                               const uint32_t* __restrict__ blkTot,
                                               uint32_t* __restrict__ offs) {
  __shared__ uint32_t s_base;
  __shared__ uint32_t wt[4];
  uint32_t tid = threadIdx.x, blk = blockIdx.x;
  if (tid < 64u) {  // wave 0: exclusive prefix over the 64 block totals
    uint32_t v = blkTot[tid];
    uint32_t incl = v;
    for (int d = 1; d < 64; d <<= 1) {
      uint32_t n = __shfl_up(incl, d, 64);
      if (tid >= (uint32_t)d) incl += n;
    }
    if (tid == blk) s_base = incl - v;
  }
  __syncthreads();
  uint32_t lane = tid & 63u, wid = tid >> 6;
  uint32_t b0 = blk * 1024u + tid * 4u;
  uint4 c = ((const uint4*)hist)[b0 >> 2];
  uint32_t s = c.x + c.y + c.z + c.w;
  uint32_t incl = s;
  for (int d = 1; d < 64; d <<= 1) {
    uint32_t n = __shfl_up(incl, d, 64);
    if (lane >= (uint32_t)d) incl += n;
  }
  if (lane == 63u) wt[wid] = incl;
  __syncthreads();
  uint32_t wbase = 0u;
  for (uint32_t w = 0; w < wid; ++w) wbase += wt[w];
  uint32_t base = s_base + wbase + (incl - s);
  ((uint4*)offs)[b0 >> 2] = make_uint4(base, base + c.x, base + c.x + c.y,
                                       base + c.x + c.y + c.z);
}

// ---------- writer: wave-autonomous, 8 keys/wave ----------
__global__ __launch_bounds__(256) void k_write(const uint32_t* __restrict__ hist,
                                               const uint32_t* __restrict__ offs,
                                               float4* __restrict__ out4) {
  __shared__ uint32_t s_off[32], s_cnt[32];
  uint32_t tid = threadIdx.x, blk = blockIdx.x;
  if (tid < 32u) {
    uint32_t k = blk * 32u + tid;
    s_off[tid] = offs[k];
    s_cnt[tid] = hist[k];
  }
  __syncthreads();
  uint32_t lane = tid & 63u, wid = tid >> 6;
  uint32_t q = lane & 3u;
  for (uint32_t kk = 0; kk < 8u; ++kk) {
    uint32_t ki = wid * 8u + kk;
    uint32_t k = blk * 32u + ki;
    uint32_t off = s_off[ki], cnt = s_cnt[ki];
    float4 pat;
    pat.x = (float)((k >> (15u - (q * 4u + 0u))) & 1u);
    pat.y = (float)((k >> (15u - (q * 4u + 1u))) & 1u);
    pat.z = (float)((k >> (15u - (q * 4u + 2u))) & 1u);
    pat.w = (float)((k >> (15u - (q * 4u + 3u))) & 1u);
    size_t base = (size_t)off * 4u;
    uint32_t tot = cnt * 4u;
    for (uint32_t j = lane; j < tot; j += 64u) out4[base + j] = pat;
  }
}

extern "C" void kernel_launch(void* const* d_in, const int* in_sizes, int n_in,
                              void* d_out, int out_size, void* d_ws, size_t ws_size,
                              hipStream_t stream) {
  const float4* in4 = (const float4*)d_in[0];
  float4* out4 = (float4*)d_out;
  uint32_t* hist = (uint32_t*)d_ws;               // 65536 u32
  uint32_t* offs = hist + BINS;                   // 65536 u32
  uint32_t* blkTot = offs + BINS;                 // 64 u32 (pad to 1024)
  uint32_t* partial = blkTot + 1024u;             // NBLK * QWORDS u32 = 32 MiB

  size_t need = ((size_t)2 * BINS + 1024u + (size_t)NBLK * QWORDS) * 4u;
  if (ws_size >= need) {
    k_hist_lds<<<NBLK, NTHR, 0, stream>>>(in4, partial);
    k_reduceB<<<64, NTHR, 0, stream>>>(partial, hist, blkTot);
  } else {
    k_zero<<<BINS / 256, 256, 0, stream>>>(hist);
    k_hist<<<SEQN / 256, 256, 0, stream>>>(in4, hist);
    k_scan1<<<64, 256, 0, stream>>>(hist, blkTot);
  }
  k_scanB<<<64, 256, 0, stream>>>(hist, blkTot, offs);
  k_write<<<BINS / 32, 256, 0, stream>>>(hist, offs, out4);
}